// Round 12
// baseline (130.716 us; speedup 1.0000x reference)
//
#include <hip/hip_runtime.h>
#include <stdint.h>

typedef __attribute__((ext_vector_type(8))) short bh8;       // 8 x bf16 (4 VGPR)
typedef __attribute__((ext_vector_type(4))) float f32x4;
typedef __attribute__((ext_vector_type(4))) unsigned short u16x4;
typedef __attribute__((ext_vector_type(8))) unsigned short u16x8;
typedef __attribute__((ext_vector_type(2))) unsigned int u32x2;

#define DEVI static __device__ __forceinline__

constexpr int B_ = 2, S_ = 2048, D_ = 1024, H_ = 16, E_ = 64;

// workspace layout (elements of ushort/bf16)
constexpr size_t OFF_XB  = 0;                              // x as bf16 [B*S, D]; DEAD after k_qkv
constexpr size_t OFF_WQT = OFF_XB  + (size_t)B_*S_*D_;     // WqT [H, E, D]  } contiguous
constexpr size_t OFF_WKT = OFF_WQT + (size_t)H_*E_*D_;     // WkT [H, E, D]  } = one
constexpr size_t OFF_WVT = OFF_WKT + (size_t)H_*E_*D_;     // WvT [H, E, D]  } [3072,1024]
constexpr size_t OFF_WOT = OFF_WVT + (size_t)H_*E_*D_;     // WoT [D, D]
constexpr size_t OFF_Q   = OFF_WOT + (size_t)D_*D_;        // Q^T [B*H, E, S] (pre-scaled by 0.125*log2e)
constexpr size_t OFF_K   = OFF_Q   + (size_t)B_*H_*S_*E_;  // [B*H, S, E]
constexpr size_t OFF_VT  = OFF_K   + (size_t)B_*H_*S_*E_;  // [B*H, E, S]
constexpr size_t OFF_O   = OFF_VT  + (size_t)B_*H_*S_*E_;  // attn out concat [B*S, D]
// split-attn partials live in the dead XB region:
constexpr size_t OFF_PO  = OFF_XB;                         // 1024 x 4096 ushort (8 MB)
constexpr size_t OFF_PML = OFF_XB + 4*1024*1024;           // 1024 x 128 float (512 KB)

DEVI unsigned short f2bf(float f) {
    union { float f; unsigned u; } v; v.f = f;
    unsigned u = v.u;
    return (unsigned short)((u + 0x7fffu + ((u >> 16) & 1u)) >> 16);
}
DEVI float bf2f(unsigned short u) {
    union { unsigned u; float f; } v; v.u = (unsigned)u << 16; return v.f;
}

DEVI unsigned cvt_pk_bf16(float lo, float hi) {   // packs {lo,hi} -> 2 bf16 in one u32
    unsigned r;
    asm("v_cvt_pk_bf16_f32 %0, %1, %2" : "=v"(r) : "v"(lo), "v"(hi));
    return r;
}

DEVI void gload16(const void* g, void* l) {
    __builtin_amdgcn_global_load_lds(
        (const __attribute__((address_space(1))) unsigned int*)g,
        (__attribute__((address_space(3))) unsigned int*)l, 16, 0, 0);
}

DEVI f32x4 mfma16(bh8 a, bh8 b, f32x4 c) {
    return __builtin_amdgcn_mfma_f32_16x16x32_bf16(a, b, c, 0, 0, 0);
}

// counted-vmcnt barrier: prefetched loads stay in flight across the barrier.
template<int N> DEVI void vm_barrier() {
    asm volatile("s_waitcnt vmcnt(%0)" :: "i"(N) : "memory");
    __builtin_amdgcn_s_barrier();
    __builtin_amdgcn_sched_barrier(0);
}
DEVI void post_barrier() {
    __builtin_amdgcn_sched_barrier(0);
    __builtin_amdgcn_s_barrier();
    __builtin_amdgcn_sched_barrier(0);
}

// ---------------- prep: x -> bf16 ----------------
__global__ __launch_bounds__(256) void k_convert_x(const float* __restrict__ x,
                                                   unsigned short* __restrict__ ws) {
    const int i = blockIdx.x * 256 + threadIdx.x;   // one float4 each; n4 = 1048576
    const float4 v = ((const float4*)x)[i];
    u16x4 o = { f2bf(v.x), f2bf(v.y), f2bf(v.z), f2bf(v.w) };
    *(u16x4*)(ws + OFF_XB + (size_t)i * 4) = o;
}

// ---------------- prep: weights -> bf16, transposed ----------------
__global__ __launch_bounds__(256) void k_transpose_w(const float* __restrict__ Wq,
                                                     const float* __restrict__ Wk,
                                                     const float* __restrict__ Wv,
                                                     const float* __restrict__ Wo,
                                                     unsigned short* __restrict__ ws) {
    const int xi = blockIdx.x;   // 0..255
    const int z  = blockIdx.y;   // 0..3
    const int t  = threadIdx.x;
    __shared__ __align__(16) unsigned short tile[64][72];

    const float* src; unsigned short* dst;
    int inCols, inBase, outBase;
    if (z < 3) {
        src = (z == 0) ? Wq : (z == 1) ? Wk : Wv;
        dst = ws + ((z == 0) ? OFF_WQT : (z == 1) ? OFF_WKT : OFF_WVT);
        inCols = 64;
        inBase = xi * 64 * 64;
        const int h = xi >> 4, dt = xi & 15;
        outBase = h * 65536 + dt * 64;
    } else {
        src = Wo; dst = ws + OFF_WOT;
        inCols = 1024;
        const int et = xi >> 4, dt = xi & 15;
        inBase  = (dt * 64) * 1024 + et * 64;
        outBase = (et * 64) * 1024 + dt * 64;
    }
#pragma unroll
    for (int v = 0; v < 4; ++v) {
        const int flat = v * 256 + t;
        const int i = flat >> 4, j4 = (flat & 15) * 4;
        const float4 val = *(const float4*)(src + inBase + i * inCols + j4);
        tile[i][j4 + 0] = f2bf(val.x);
        tile[i][j4 + 1] = f2bf(val.y);
        tile[i][j4 + 2] = f2bf(val.z);
        tile[i][j4 + 3] = f2bf(val.w);
    }
    __syncthreads();
    const int j = t >> 2, iseg = (t & 3) * 16;
    u16x8 p0, p1;
#pragma unroll
    for (int u = 0; u < 8; ++u) p0[u] = tile[iseg + u][j];
#pragma unroll
    for (int u = 0; u < 8; ++u) p1[u] = tile[iseg + 8 + u][j];
    *(u16x8*)(dst + outBase + (size_t)j * 1024 + iseg)     = p0;
    *(u16x8*)(dst + outBase + (size_t)j * 1024 + iseg + 8) = p1;
}

// ---------------- GEMM mainloop: C(128x128) = A(128x1024) * B^T(128x1024)^T ----------------
// 3 LDS buffers, stage-at-top rotation -> one barrier per k-step.
DEVI void gemm_tile_128x128(const unsigned short* __restrict__ A,
                            const unsigned short* __restrict__ Bw,
                            unsigned short* lds,
                            f32x4 acc[2][8]) {
    const int lane = threadIdx.x & 63;
    const int w    = threadIdx.x >> 6;
    const int lr = lane & 15, lg = lane >> 4;
    const unsigned short* a0 = A  + (size_t)((w * 2 + 0) * 16 + lr) * D_ + lg * 8;
    const unsigned short* a1 = A  + (size_t)((w * 2 + 1) * 16 + lr) * D_ + lg * 8;
    const unsigned short* b0 = Bw + (size_t)((w * 2 + 0) * 16 + lr) * D_ + lg * 8;
    const unsigned short* b1 = Bw + (size_t)((w * 2 + 1) * 16 + lr) * D_ + lg * 8;
    const int oA0 = (w * 2 + 0) * 512, oA1 = (w * 2 + 1) * 512;
    const int oB0 = 4096 + oA0,        oB1 = 4096 + oA1;

    auto stage = [&](int ks, int bufi) {
        unsigned short* base = lds + bufi * 8192;
        gload16(a0 + ks * 32, base + oA0);
        gload16(a1 + ks * 32, base + oA1);
        gload16(b0 + ks * 32, base + oB0);
        gload16(b1 + ks * 32, base + oB1);
    };

    stage(0, 0); stage(1, 1);
    for (int ks = 0; ks < 32; ++ks) {
        if (ks < 31) vm_barrier<4>();
        else         vm_barrier<0>();
        if (ks + 2 < 32) stage(ks + 2, (ks + 2) % 3);
        const unsigned short* base = lds + (ks % 3) * 8192;
        bh8 af0 = *(const bh8*)(base + (w * 2 + 0) * 512 + lane * 8);
        bh8 af1 = *(const bh8*)(base + (w * 2 + 1) * 512 + lane * 8);
#pragma unroll
        for (int nt = 0; nt < 8; ++nt) {
            bh8 bf = *(const bh8*)(base + 4096 + nt * 512 + lane * 8);
            acc[0][nt] = mfma16(af0, bf, acc[0][nt]);
            acc[1][nt] = mfma16(af1, bf, acc[1][nt]);
        }
        __builtin_amdgcn_sched_barrier(0);
    }
}

// ---------------- fused QKV projection: C[4096,3072] = XB * [WqT;WkT;WvT]^T ----------------
__global__ __launch_bounds__(256, 3) void k_qkv(unsigned short* __restrict__ ws,
                                                const float* __restrict__ bq,
                                                const float* __restrict__ bk,
                                                const float* __restrict__ bv) {
    const int flat  = blockIdx.x;          // 0..767
    const int idx   = flat >> 3;           // 0..95
    const int stile = (flat & 7) * 4 + (idx & 3);   // 0..31 (128 rows each)
    const int ntile = idx >> 2;            // 0..23 (128 cols each of 3072)
    const int row0  = stile * 128;
    const unsigned short* A  = ws + OFF_XB  + (size_t)row0 * D_;
    const unsigned short* Bw = ws + OFF_WQT + (size_t)ntile * 128 * D_;

    __shared__ __align__(16) unsigned short lds[3 * 8192];
    f32x4 acc[2][8];
#pragma unroll
    for (int i = 0; i < 2; ++i)
#pragma unroll
        for (int j = 0; j < 8; ++j) acc[i][j] = (f32x4){0.f, 0.f, 0.f, 0.f};

    gemm_tile_128x128(A, Bw, lds, acc);

    const int lane = threadIdx.x & 63, w = threadIdx.x >> 6;
    const int lr = lane & 15, lg = lane >> 4;
    const int srow0 = row0 + w * 32;
    const int b     = srow0 >> 11;
    const int sl0   = srow0 & (S_ - 1);
#pragma unroll
    for (int mt = 0; mt < 2; ++mt) {
#pragma unroll
        for (int nt = 0; nt < 8; ++nt) {
            const int gcol = ntile * 128 + nt * 16;
            const int mat  = gcol >> 10;
            const int h    = (gcol >> 6) & 15;
            const int e    = (gcol & 63) + lr;
            const int bh   = b * H_ + h;
            const float bia = ((mat == 0) ? bq : (mat == 1) ? bk : bv)[h * 64 + e];
            if (mat == 0) {        // Q^T [BH][E][S], packed along s, pre-scaled
                u16x4 pk;
#pragma unroll
                for (int r = 0; r < 4; ++r)
                    pk[r] = f2bf((acc[mt][nt][r] + bia) * 0.1803368801f);  // 1/8*log2(e)
                const int sl = sl0 + mt * 16 + lg * 4;
                *(u16x4*)(ws + OFF_Q + ((size_t)(bh * E_ + e)) * S_ + sl) = pk;
            } else if (mat == 2) { // V^T [BH][E][S]
                u16x4 pk;
#pragma unroll
                for (int r = 0; r < 4; ++r) pk[r] = f2bf(acc[mt][nt][r] + bia);
                const int sl = sl0 + mt * 16 + lg * 4;
                *(u16x4*)(ws + OFF_VT + ((size_t)(bh * E_ + e)) * S_ + sl) = pk;
            } else {               // K [BH][S][E]
#pragma unroll
                for (int r = 0; r < 4; ++r) {
                    const int sl = sl0 + mt * 16 + lg * 4 + r;
                    ws[OFF_K + ((size_t)bh * S_ + sl) * E_ + e] = f2bf(acc[mt][nt][r] + bia);
                }
            }
        }
    }
}

// ---------------- flash attention (causal), swapped-QK^T, SPLIT-K for qt>=16 ----------------
// flat < 1024: split blocks. half 0 computes k-tiles [0,h), half 1 [h,qt+1), h=(qt+2)>>1.
//   Partials (unnormalized O bf16 + per-row m,l f32) -> dead XB region; k_merge combines.
// flat >= 1024: qt < 16, single block writes OFF_O directly.
// Max sequential chain: 17 k-tiles (was 32). Grid 1536 -> scheduler backfill exists.
__global__ __launch_bounds__(256, 4) void k_attn(unsigned short* __restrict__ ws) {
    const int flat = blockIdx.x;          // 0..1535
    int qt, j, kt_begin, kt_end, part;
    if (flat < 1024) {
        const int s = flat & 511;
        part = flat >> 9;                 // 0 or 1
        qt = 31 - (s >> 5);               // 31..16, heavy first
        j  = s & 31;
        const int h = (qt + 2) >> 1;
        kt_begin = part ? h : 0;
        kt_end   = part ? qt + 1 : h;
    } else {
        const int s2 = flat - 1024;
        qt = 15 - (s2 >> 5);              // 15..0
        j  = s2 & 31;
        kt_begin = 0; kt_end = qt + 1; part = -1;
    }
    const int bh = (j & 7) * 4 + (j >> 3);   // XCD = flat&7 owns 4 bh values
    const int lane = threadIdx.x & 63, w = threadIdx.x >> 6;
    const int lr = lane & 15, lg = lane >> 4;
    const unsigned short* Qp = ws + OFF_Q  + (size_t)bh * E_ * S_;   // Q^T [E][S]
    const unsigned short* Kp = ws + OFF_K  + (size_t)bh * S_ * E_;
    const unsigned short* Vp = ws + OFF_VT + (size_t)bh * E_ * S_;
    __shared__ __align__(16) unsigned short ldsK[2][8 * 512];
    __shared__ __align__(16) unsigned short ldsV[2][8 * 512];
    __shared__ __align__(16) unsigned short ldsP[4 * 1024];   // per-wave 16x64 P (wave-private)

    const int qbase = qt * 64 + w * 16;   // this wave's 16 q rows
    bh8 qf[2];
#pragma unroll
    for (int kg = 0; kg < 2; ++kg) {
        bh8 t;
#pragma unroll
        for (int i = 0; i < 8; ++i)
            t[i] = (short)Qp[(size_t)(kg * 32 + lg * 8 + i) * S_ + qbase + lr];
        qf[kg] = t;
    }

    f32x4 o[4];
    float m = -3.0e38f, l = 0.f;    // per-lane online state for q = lr (replicated over lg)
#pragma unroll
    for (int i = 0; i < 4; ++i) o[i] = (f32x4){0.f, 0.f, 0.f, 0.f};

    auto stage = [&](int kt, int bufi) {
        const int sk0 = kt * 64;
#pragma unroll
        for (int u = 0; u < 2; ++u) {
            const int blk = w * 2 + u;
            const int ct = blk >> 1, kg = blk & 1;
            gload16(Kp + (size_t)(sk0 + ct * 16 + lr) * E_ + kg * 32 + lg * 8,
                    &ldsK[bufi][blk * 512]);
            gload16(Vp + (size_t)(ct * 16 + lr) * S_ + sk0 + kg * 32 + lg * 8,
                    &ldsV[bufi][blk * 512]);
        }
    };

    unsigned short* Pw = ldsP + w * 1024;

    stage(kt_begin, 0);
    if (kt_begin + 1 < kt_end) stage(kt_begin + 1, 1);

    for (int kt = kt_begin; kt < kt_end; ++kt) {
        if (kt + 1 < kt_end) vm_barrier<4>();
        else                 vm_barrier<0>();
        const int cur = (kt - kt_begin) & 1;
        const unsigned short* Kc = ldsK[cur];
        const unsigned short* Vc = ldsV[cur];

        // S^T = K Q^T (swapped): sc[ct][r] = score[s_k = ct*16+lg*4+r][q = lr]
        f32x4 sc[4];
#pragma unroll
        for (int ct = 0; ct < 4; ++ct) sc[ct] = (f32x4){0.f, 0.f, 0.f, 0.f};
#pragma unroll
        for (int ct = 0; ct < 4; ++ct)
#pragma unroll
            for (int kg = 0; kg < 2; ++kg) {
                bh8 kf = *(const bh8*)(Kc + (ct * 2 + kg) * 512 + lane * 8);
                sc[ct] = mfma16(kf, qf[kg], sc[ct]);
            }
        // causal mask: diagonal tile only (only part B / single blocks reach kt==qt)
        if (kt == qt) {
#pragma unroll
            for (int ct = 0; ct < 4; ++ct) {
                const int skl = ct * 16 + lg * 4;
#pragma unroll
                for (int r = 0; r < 4; ++r)
                    if (skl + r > w * 16 + lr) sc[ct][r] = -3.0e38f;
            }
        }
        // column (q) max: 15 in-lane fmax + 2 shfl
        float mx = fmaxf(fmaxf(sc[0][0], sc[0][1]), fmaxf(sc[0][2], sc[0][3]));
#pragma unroll
        for (int ct = 1; ct < 4; ++ct)
            mx = fmaxf(mx, fmaxf(fmaxf(sc[ct][0], sc[ct][1]),
                                 fmaxf(sc[ct][2], sc[ct][3])));
        mx = fmaxf(mx, __shfl_xor(mx, 16, 64));
        mx = fmaxf(mx, __shfl_xor(mx, 32, 64));
        // defer-max (T13): rescale only when max grew by > 8 (log2 domain)
        const bool need = mx > m + 8.0f;
        if (__any(need)) {
            const float mn = need ? mx : m;
            const float sf = __builtin_amdgcn_exp2f(m - mn);   // 1.0 when !need
            m = mn;
            l *= sf;
#pragma unroll
            for (int r = 0; r < 4; ++r) {
                const float sfq = __shfl(sf, (lane & 48) + lg * 4 + r, 64);
#pragma unroll
                for (int et = 0; et < 4; ++et) o[et][r] *= sfq;
            }
        }
        // P = exp2(S - m), partial sum in-lane
        float rs = 0.f;
#pragma unroll
        for (int ct = 0; ct < 4; ++ct)
#pragma unroll
            for (int r = 0; r < 4; ++r) {
                float p = __builtin_amdgcn_exp2f(sc[ct][r] - m);
                sc[ct][r] = p;
                rs += p;
            }
        rs += __shfl_xor(rs, 16, 64);
        rs += __shfl_xor(rs, 32, 64);
        l += rs;
        // pack P (cvt_pk) and write A-frag order: 4 x ds_write_b64
#pragma unroll
        for (int ct = 0; ct < 4; ++ct) {
            u32x2 pk = { cvt_pk_bf16(sc[ct][0], sc[ct][1]),
                         cvt_pk_bf16(sc[ct][2], sc[ct][3]) };
            const int addr = (ct >> 1) * 512 +
                             ((((ct & 1) * 2) + (lg >> 1)) * 16 + lr) * 8 + (lg & 1) * 4;
            *(u32x2*)(Pw + addr) = pk;
        }
        // O += P V  (wave-private P; lgkm-ordered, no barrier)
#pragma unroll
        for (int skg = 0; skg < 2; ++skg) {
            bh8 pf = *(const bh8*)(Pw + skg * 512 + lane * 8);
#pragma unroll
            for (int et = 0; et < 4; ++et) {
                bh8 vf = *(const bh8*)(Vc + (et * 2 + skg) * 512 + lane * 8);
                o[et] = mfma16(pf, vf, o[et]);
            }
        }
        post_barrier();
        if (kt + 2 < kt_end) stage(kt + 2, cur);
    }
    if (part < 0) {
        // epilogue: O/l -> concat layout [B,S,H*64]; l lives at lane with lr = q
        const int b = bh >> 4, hh = bh & 15;
#pragma unroll
        for (int r = 0; r < 4; ++r) {
            const float lq = __shfl(l, (lane & 48) + lg * 4 + r, 64);
            const float inv = 1.0f / lq;
            const int s = qbase + lg * 4 + r;
#pragma unroll
            for (int et = 0; et < 4; ++et)
                ws[OFF_O + ((size_t)(b * S_ + s)) * D_ + hh * E_ + et * 16 + lr] =
                    f2bf(o[et][r] * inv);
        }
    } else {
        // partial epilogue: unnormalized O (bf16) + per-row m,l (f32)
        const int p = ((qt - 16) * 32 + bh) * 2 + part;
        unsigned short* Op = ws + OFF_PO + (size_t)p * 4096;   // [64 rows][64 cols]
        float* mlb = (float*)(ws + OFF_PML) + p * 128;
#pragma unroll
        for (int r = 0; r < 4; ++r) {
            const int row = w * 16 + lg * 4 + r;
#pragma unroll
            for (int et = 0; et < 4; ++et)
                Op[row * 64 + et * 16 + lr] = f2bf(o[et][r]);
        }
        if (lg == 0) {               // lanes 0..15 hold m,l for rows w*16+lr
            mlb[(w * 16 + lr) * 2]     = m;
            mlb[(w * 16 + lr) * 2 + 1] = l;
        }
    }
}

// ---------------- merge split-attn partials (qt >= 16) ----------------
__global__ __launch_bounds__(256) void k_merge(unsigned short* __restrict__ ws) {
    const int qi = blockIdx.x >> 5;        // 0..15
    const int qt = 16 + qi;
    const int j  = blockIdx.x & 31;
    const int bh = (j & 7) * 4 + (j >> 3); // same XCD as the writers (flat&7 == j&7)
    const int p0 = ((qt - 16) * 32 + bh) * 2;
    const unsigned short* Oa = ws + OFF_PO + (size_t)p0 * 4096;
    const unsigned short* Ob = Oa + 4096;
    const float* mla = (const float*)(ws + OFF_PML) + p0 * 128;
    const float* mlb = mla + 128;

    const int t = threadIdx.x;
    const int row = t >> 2, cg = t & 3;    // 64 rows x 4 col-groups of 16
    const float ma = mla[row * 2], la = mla[row * 2 + 1];
    const float mb = mlb[row * 2], lb = mlb[row * 2 + 1];
    const float mm = fmaxf(ma, mb);
    const float sa = __builtin_amdgcn_exp2f(ma - mm);
    const float sb = __builtin_amdgcn_exp2f(mb - mm);
    const float inv = 1.0f / (la * sa + lb * sb);

    u16x8 va0 = *(const u16x8*)(Oa + row * 64 + cg * 16);
    u16x8 va1 = *(const u16x8*)(Oa + row * 64 + cg * 16 + 8);
    u16x8 vb0 = *(const u16x8*)(Ob + row * 64 + cg * 16);
    u16x8 vb1 = *(const u16x8*)(Ob + row * 64 + cg * 16 + 8);
    u16x8 o0, o1;
#pragma unroll
    for (int i = 0; i < 8; ++i) {
        o0[i] = f2bf((bf2f(va0[i]) * sa + bf2f(vb0[i]) * sb) * inv);
        o1[i] = f2bf((bf2f(va1[i]) * sa + bf2f(vb1[i]) * sb) * inv);
    }
    const int b = bh >> 4, hh = bh & 15;
    const int s = qt * 64 + row;
    unsigned short* dst = ws + OFF_O + ((size_t)(b * S_ + s)) * D_ + hh * E_ + cg * 16;
    *(u16x8*)(dst)     = o0;
    *(u16x8*)(dst + 8) = o1;
}

// ---------------- output projection: C[4096,1024] = O * WoT^T ----------------
__global__ __launch_bounds__(256, 3) void k_oproj(const unsigned short* __restrict__ ws,
                                                  const float* __restrict__ bo,
                                                  float* __restrict__ out) {
    const int flat  = blockIdx.x;          // 0..255
    const int idx   = flat >> 3;           // 0..31
    const int stile = (flat & 7) * 4 + (idx & 3);   // 0..31
    const int ntile = idx >> 2;            // 0..7 (128 cols each)
    const unsigned short* A  = ws + OFF_O   + (size_t)stile * 128 * D_;
    const unsigned short* Bw = ws + OFF_WOT + (size_t)ntile * 128 * D_;
    __shared__ __align__(16) unsigned short lds[3 * 8192];
    f32x4 acc[2][8];
#pragma unroll
    for (int i = 0; i < 2; ++i)
#pragma unroll
        for (int j = 0; j < 8; ++j) acc[i][j] = (f32x4){0.f, 0.f, 0.f, 0.f};

    gemm_tile_128x128(A, Bw, lds, acc);

    const int lane = threadIdx.x & 63, w = threadIdx.x >> 6;
    const int lr = lane & 15, lg = lane >> 4;
    const int r0 = stile * 128 + w * 32;
#pragma unroll
    for (int mt = 0; mt < 2; ++mt)
#pragma unroll
        for (int nt = 0; nt < 8; ++nt) {
            const int e = ntile * 128 + nt * 16 + lr;
            const float bia = bo[e];
#pragma unroll
            for (int r = 0; r < 4; ++r)
                out[(size_t)(r0 + mt * 16 + lg * 4 + r) * D_ + e] = acc[mt][nt][r] + bia;
        }
}

extern "C" void kernel_launch(void* const* d_in, const int* in_sizes, int n_in,
                              void* d_out, int out_size, void* d_ws, size_t ws_size,
                              hipStream_t stream) {
    const float* x  = (const float*)d_in[0];
    const float* Wq = (const float*)d_in[1];
    const float* bq = (const float*)d_in[2];
    const float* Wk = (const float*)d_in[3];
    const float* bk = (const float*)d_in[4];
    const float* Wv = (const float*)d_in[5];
    const float* bv = (const float*)d_in[6];
    const float* Wo = (const float*)d_in[7];
    const float* bo = (const float*)d_in[8];
    float* out = (float*)d_out;
    unsigned short* ws = (unsigned short*)d_ws;

    k_convert_x<<<dim3((B_ * S_ * D_) / 4 / 256), 256, 0, stream>>>(x, ws);
    k_transpose_w<<<dim3(256, 4), 256, 0, stream>>>(Wq, Wk, Wv, Wo, ws);
    k_qkv<<<dim3(768), 256, 0, stream>>>(ws, bq, bk, bv);
    k_attn<<<dim3(1536), 256, 0, stream>>>(ws);
    k_merge<<<dim3(512), 256, 0, stream>>>(ws);
    k_oproj<<<dim3(256), 256, 0, stream>>>(ws, bo, out);
}

// Round 13
// 118.896 us; speedup vs baseline: 1.0994x; 1.0994x over previous
//
#include <hip/hip_runtime.h>
#include <stdint.h>

typedef __attribute__((ext_vector_type(8))) short bh8;       // 8 x bf16 (4 VGPR)
typedef __attribute__((ext_vector_type(4))) float f32x4;
typedef __attribute__((ext_vector_type(4))) unsigned short u16x4;
typedef __attribute__((ext_vector_type(8))) unsigned short u16x8;
typedef __attribute__((ext_vector_type(2))) unsigned int u32x2;

#define DEVI static __device__ __forceinline__

constexpr int B_ = 2, S_ = 2048, D_ = 1024, H_ = 16, E_ = 64;

// workspace layout (elements of ushort/bf16)
constexpr size_t OFF_XB  = 0;                              // x as bf16 [B*S, D]
constexpr size_t OFF_WQT = OFF_XB  + (size_t)B_*S_*D_;     // WqT [H, E, D]  } contiguous
constexpr size_t OFF_WKT = OFF_WQT + (size_t)H_*E_*D_;     // WkT [H, E, D]  } = one
constexpr size_t OFF_WVT = OFF_WKT + (size_t)H_*E_*D_;     // WvT [H, E, D]  } [3072,1024]
constexpr size_t OFF_WOT = OFF_WVT + (size_t)H_*E_*D_;     // WoT [D, D]
constexpr size_t OFF_Q   = OFF_WOT + (size_t)D_*D_;        // Q^T [B*H, E, S] (pre-scaled by 0.125*log2e)
constexpr size_t OFF_K   = OFF_Q   + (size_t)B_*H_*S_*E_;  // [B*H, S, E]
constexpr size_t OFF_VT  = OFF_K   + (size_t)B_*H_*S_*E_;  // [B*H, E, S]
constexpr size_t OFF_O   = OFF_VT  + (size_t)B_*H_*S_*E_;  // attn out concat [B*S, D]

DEVI unsigned short f2bf(float f) {
    union { float f; unsigned u; } v; v.f = f;
    unsigned u = v.u;
    return (unsigned short)((u + 0x7fffu + ((u >> 16) & 1u)) >> 16);
}

DEVI unsigned cvt_pk_bf16(float lo, float hi) {   // packs {lo,hi} -> 2 bf16 in one u32
    unsigned r;
    asm("v_cvt_pk_bf16_f32 %0, %1, %2" : "=v"(r) : "v"(lo), "v"(hi));
    return r;
}

DEVI void gload16(const void* g, void* l) {
    __builtin_amdgcn_global_load_lds(
        (const __attribute__((address_space(1))) unsigned int*)g,
        (__attribute__((address_space(3))) unsigned int*)l, 16, 0, 0);
}

DEVI f32x4 mfma16(bh8 a, bh8 b, f32x4 c) {
    return __builtin_amdgcn_mfma_f32_16x16x32_bf16(a, b, c, 0, 0, 0);
}

// counted-vmcnt barrier: prefetched loads stay in flight across the barrier.
template<int N> DEVI void vm_barrier() {
    asm volatile("s_waitcnt vmcnt(%0)" :: "i"(N) : "memory");
    __builtin_amdgcn_s_barrier();
    __builtin_amdgcn_sched_barrier(0);
}
DEVI void post_barrier() {
    __builtin_amdgcn_sched_barrier(0);
    __builtin_amdgcn_s_barrier();
    __builtin_amdgcn_sched_barrier(0);
}

// ---------------- prep: x -> bf16 ----------------
__global__ __launch_bounds__(256) void k_convert_x(const float* __restrict__ x,
                                                   unsigned short* __restrict__ ws) {
    const int i = blockIdx.x * 256 + threadIdx.x;   // one float4 each; n4 = 1048576
    const float4 v = ((const float4*)x)[i];
    u16x4 o = { f2bf(v.x), f2bf(v.y), f2bf(v.z), f2bf(v.w) };
    *(u16x4*)(ws + OFF_XB + (size_t)i * 4) = o;
}

// ---------------- prep: weights -> bf16, transposed ----------------
__global__ __launch_bounds__(256) void k_transpose_w(const float* __restrict__ Wq,
                                                     const float* __restrict__ Wk,
                                                     const float* __restrict__ Wv,
                                                     const float* __restrict__ Wo,
                                                     unsigned short* __restrict__ ws) {
    const int xi = blockIdx.x;   // 0..255
    const int z  = blockIdx.y;   // 0..3
    const int t  = threadIdx.x;
    __shared__ __align__(16) unsigned short tile[64][72];

    const float* src; unsigned short* dst;
    int inCols, inBase, outBase;
    if (z < 3) {
        src = (z == 0) ? Wq : (z == 1) ? Wk : Wv;
        dst = ws + ((z == 0) ? OFF_WQT : (z == 1) ? OFF_WKT : OFF_WVT);
        inCols = 64;
        inBase = xi * 64 * 64;
        const int h = xi >> 4, dt = xi & 15;
        outBase = h * 65536 + dt * 64;
    } else {
        src = Wo; dst = ws + OFF_WOT;
        inCols = 1024;
        const int et = xi >> 4, dt = xi & 15;
        inBase  = (dt * 64) * 1024 + et * 64;
        outBase = (et * 64) * 1024 + dt * 64;
    }
#pragma unroll
    for (int v = 0; v < 4; ++v) {
        const int flat = v * 256 + t;
        const int i = flat >> 4, j4 = (flat & 15) * 4;
        const float4 val = *(const float4*)(src + inBase + i * inCols + j4);
        tile[i][j4 + 0] = f2bf(val.x);
        tile[i][j4 + 1] = f2bf(val.y);
        tile[i][j4 + 2] = f2bf(val.z);
        tile[i][j4 + 3] = f2bf(val.w);
    }
    __syncthreads();
    const int j = t >> 2, iseg = (t & 3) * 16;
    u16x8 p0, p1;
#pragma unroll
    for (int u = 0; u < 8; ++u) p0[u] = tile[iseg + u][j];
#pragma unroll
    for (int u = 0; u < 8; ++u) p1[u] = tile[iseg + 8 + u][j];
    *(u16x8*)(dst + outBase + (size_t)j * 1024 + iseg)     = p0;
    *(u16x8*)(dst + outBase + (size_t)j * 1024 + iseg + 8) = p1;
}

// ================= qkv 256x256 8-phase machinery =================
// LDS: A = lds[0..32768), B = lds[32768..65536); per buffer (kt&1) 16384 elem.
// Fragment-order: A frag (mfrag, ks) at b*16384 + (mfrag*2+ks)*512 + lane*8.
DEVI void qkv_stA(const unsigned short* Ap, unsigned short* lds, int kt, int mh, int ks,
                  int lane, int w, int lr, int lg) {
    const int b = kt & 1;
    const int mfrag = (w >> 2) * 8 + mh * 4 + (w & 3);
    gload16(Ap + (size_t)(mfrag * 16 + lr) * D_ + kt * 64 + ks * 32 + lg * 8,
            lds + b * 16384 + (mfrag * 2 + ks) * 512 + lane * 8);
}
DEVI void qkv_stB(const unsigned short* Bp, unsigned short* lds, int kt, int ks,
                  int lane, int w, int lr, int lg) {
    const int b = kt & 1;
#pragma unroll
    for (int u = 0; u < 2; ++u) {
        const int nfrag = w * 2 + u;
        gload16(Bp + (size_t)(nfrag * 16 + lr) * D_ + kt * 64 + ks * 32 + lg * 8,
                lds + 32768 + b * 16384 + (nfrag * 2 + ks) * 512 + lane * 8);
    }
}
DEVI bh8 qkv_ldA(const unsigned short* lds, int b, int mfrag, int ks, int lane) {
    return *(const bh8*)(lds + b * 16384 + (mfrag * 2 + ks) * 512 + lane * 8);
}
DEVI bh8 qkv_ldB(const unsigned short* lds, int b, int nfrag, int ks, int lane) {
    return *(const bh8*)(lds + 32768 + b * 16384 + (nfrag * 2 + ks) * 512 + lane * 8);
}

// One K-tile = 4 phases. Phase: vmcnt+barrier -> ds_read subtile -> stage freed
// region -> setprio(1) -> 16 MFMA -> setprio(0) -> sched_barrier(0).
// FIFO ledger (per-thread): stages/K-tile = [p1: Aq00+Bk0 (3)][p2: Aq10 (1)]
// [p3: Aq01+Bk1 (3)][next p0: Aq11 (1)] for kt+2 (kt+1 for the p0 slot); every
// phase's needed region has exactly 12 younger loads -> uniform vmcnt(12).
template<int V0, int V1, int V2, int V3, bool S0, bool S123>
DEVI void qkv_ktile(int kt, const unsigned short* Ap, const unsigned short* Bp,
                    unsigned short* lds, int lane, int w, int lr, int lg,
                    int wm, int wn, f32x4 (&acc)[8][4]) {
    const int b = kt & 1;
    bh8 af[4], bf[4];
    // ---- phase 0: quad(mh=0, ks=0); stage A(1,1) of kt+1 ----
    vm_barrier<V0>();
#pragma unroll
    for (int n = 0; n < 4; ++n) bf[n] = qkv_ldB(lds, b, wn * 4 + n, 0, lane);
#pragma unroll
    for (int q = 0; q < 4; ++q) af[q] = qkv_ldA(lds, b, wm * 8 + q, 0, lane);
    if (S0) qkv_stA(Ap, lds, kt + 1, 1, 1, lane, w, lr, lg);
    __builtin_amdgcn_s_setprio(1);
#pragma unroll
    for (int q = 0; q < 4; ++q)
#pragma unroll
        for (int n = 0; n < 4; ++n) acc[q][n] = mfma16(af[q], bf[n], acc[q][n]);
    __builtin_amdgcn_s_setprio(0);
    __builtin_amdgcn_sched_barrier(0);
    // ---- phase 1: quad(1,0); stage A(0,0)+B(ks0) of kt+2 ----
    vm_barrier<V1>();
#pragma unroll
    for (int q = 0; q < 4; ++q) af[q] = qkv_ldA(lds, b, wm * 8 + 4 + q, 0, lane);
    if (S123) {
        qkv_stA(Ap, lds, kt + 2, 0, 0, lane, w, lr, lg);
        qkv_stB(Bp, lds, kt + 2, 0, lane, w, lr, lg);
    }
    __builtin_amdgcn_s_setprio(1);
#pragma unroll
    for (int q = 0; q < 4; ++q)
#pragma unroll
        for (int n = 0; n < 4; ++n) acc[4 + q][n] = mfma16(af[q], bf[n], acc[4 + q][n]);
    __builtin_amdgcn_s_setprio(0);
    __builtin_amdgcn_sched_barrier(0);
    // ---- phase 2: quad(0,1); stage A(1,0) of kt+2 ----
    vm_barrier<V2>();
#pragma unroll
    for (int n = 0; n < 4; ++n) bf[n] = qkv_ldB(lds, b, wn * 4 + n, 1, lane);
#pragma unroll
    for (int q = 0; q < 4; ++q) af[q] = qkv_ldA(lds, b, wm * 8 + q, 1, lane);
    if (S123) qkv_stA(Ap, lds, kt + 2, 1, 0, lane, w, lr, lg);
    __builtin_amdgcn_s_setprio(1);
#pragma unroll
    for (int q = 0; q < 4; ++q)
#pragma unroll
        for (int n = 0; n < 4; ++n) acc[q][n] = mfma16(af[q], bf[n], acc[q][n]);
    __builtin_amdgcn_s_setprio(0);
    __builtin_amdgcn_sched_barrier(0);
    // ---- phase 3: quad(1,1); stage A(0,1)+B(ks1) of kt+2 ----
    vm_barrier<V3>();
#pragma unroll
    for (int q = 0; q < 4; ++q) af[q] = qkv_ldA(lds, b, wm * 8 + 4 + q, 1, lane);
    if (S123) {
        qkv_stA(Ap, lds, kt + 2, 0, 1, lane, w, lr, lg);
        qkv_stB(Bp, lds, kt + 2, 1, lane, w, lr, lg);
    }
    __builtin_amdgcn_s_setprio(1);
#pragma unroll
    for (int q = 0; q < 4; ++q)
#pragma unroll
        for (int n = 0; n < 4; ++n) acc[4 + q][n] = mfma16(af[q], bf[n], acc[4 + q][n]);
    __builtin_amdgcn_s_setprio(0);
    __builtin_amdgcn_sched_barrier(0);
}

// ---------------- fused QKV projection: 256x256 tiles, 8 waves, 8-phase ----------------
__global__ __launch_bounds__(512, 2) void k_qkv(unsigned short* __restrict__ ws,
                                                const float* __restrict__ bq,
                                                const float* __restrict__ bk,
                                                const float* __restrict__ bv) {
    const int flat  = blockIdx.x;                   // 0..191
    const int idx   = flat >> 3;                    // 0..23
    const int stile = (flat & 7) * 2 + (idx & 1);   // 0..15 (256 rows each)
    const int ntile = idx >> 1;                     // 0..11 (256 cols each of 3072)
    const unsigned short* Ap = ws + OFF_XB  + (size_t)stile * 256 * D_;
    const unsigned short* Bp = ws + OFF_WQT + (size_t)ntile * 256 * D_;

    __shared__ __align__(16) unsigned short lds[65536];   // 128 KB
    const int tid = threadIdx.x, lane = tid & 63, w = tid >> 6;
    const int lr = lane & 15, lg = lane >> 4;
    const int wm = w >> 2, wn = w & 3;               // wave tile: rows wm*128, cols wn*64

    f32x4 acc[8][4];
#pragma unroll
    for (int i = 0; i < 8; ++i)
#pragma unroll
        for (int j = 0; j < 4; ++j) acc[i][j] = (f32x4){0.f, 0.f, 0.f, 0.f};

    // prologue: kt0 full (8) + kt1 minus A(1,1) (7), in steady-state FIFO order
    qkv_stA(Ap, lds, 0, 0, 0, lane, w, lr, lg);
    qkv_stB(Bp, lds, 0, 0, lane, w, lr, lg);
    qkv_stA(Ap, lds, 0, 1, 0, lane, w, lr, lg);
    qkv_stA(Ap, lds, 0, 0, 1, lane, w, lr, lg);
    qkv_stB(Bp, lds, 0, 1, lane, w, lr, lg);
    qkv_stA(Ap, lds, 0, 1, 1, lane, w, lr, lg);
    qkv_stA(Ap, lds, 1, 0, 0, lane, w, lr, lg);
    qkv_stB(Bp, lds, 1, 0, lane, w, lr, lg);
    qkv_stA(Ap, lds, 1, 1, 0, lane, w, lr, lg);
    qkv_stA(Ap, lds, 1, 0, 1, lane, w, lr, lg);
    qkv_stB(Bp, lds, 1, 1, lane, w, lr, lg);

    for (int kt = 0; kt < 14; ++kt)
        qkv_ktile<12, 12, 12, 12, true, true>(kt, Ap, Bp, lds, lane, w, lr, lg, wm, wn, acc);
    qkv_ktile<12, 12, 9, 8, true, false>(14, Ap, Bp, lds, lane, w, lr, lg, wm, wn, acc);
    qkv_ktile<5, 4, 1, 0, false, false>(15, Ap, Bp, lds, lane, w, lr, lg, wm, wn, acc);

    // epilogue: wave writes one head's 64-col slab. c = ntile*4+wn in 0..47
    const int c = ntile * 4 + wn;
    const int mat = c >> 4, h = c & 15;
    const float* bias = ((mat == 0) ? bq : (mat == 1) ? bk : bv) + h * 64;
    const int bb = stile >> 3;                       // batch (256 | 2048, no straddle)
    const int bh = bb * H_ + h;
#pragma unroll
    for (int mf = 0; mf < 8; ++mf) {
        const int sl = ((stile * 256 + wm * 128 + mf * 16) & (S_ - 1)) + lg * 4;
#pragma unroll
        for (int nf = 0; nf < 4; ++nf) {
            const int e = nf * 16 + lr;
            const float bia = bias[e];
            if (mat == 0) {        // Q^T [BH][E][S], pre-scaled by 0.125*log2e
                u16x4 pk;
#pragma unroll
                for (int r = 0; r < 4; ++r)
                    pk[r] = f2bf((acc[mf][nf][r] + bia) * 0.1803368801f);
                *(u16x4*)(ws + OFF_Q + ((size_t)(bh * E_ + e)) * S_ + sl) = pk;
            } else if (mat == 2) { // V^T [BH][E][S]
                u16x4 pk;
#pragma unroll
                for (int r = 0; r < 4; ++r) pk[r] = f2bf(acc[mf][nf][r] + bia);
                *(u16x4*)(ws + OFF_VT + ((size_t)(bh * E_ + e)) * S_ + sl) = pk;
            } else {               // K [BH][S][E]
#pragma unroll
                for (int r = 0; r < 4; ++r)
                    ws[OFF_K + ((size_t)bh * S_ + sl + r) * E_ + e] =
                        f2bf(acc[mf][nf][r] + bia);
            }
        }
    }
}

// ---------------- GEMM mainloop: C(128x128) (oproj) ----------------
DEVI void gemm_tile_128x128(const unsigned short* __restrict__ A,
                            const unsigned short* __restrict__ Bw,
                            unsigned short* lds,
                            f32x4 acc[2][8]) {
    const int lane = threadIdx.x & 63;
    const int w    = threadIdx.x >> 6;
    const int lr = lane & 15, lg = lane >> 4;
    const unsigned short* a0 = A  + (size_t)((w * 2 + 0) * 16 + lr) * D_ + lg * 8;
    const unsigned short* a1 = A  + (size_t)((w * 2 + 1) * 16 + lr) * D_ + lg * 8;
    const unsigned short* b0 = Bw + (size_t)((w * 2 + 0) * 16 + lr) * D_ + lg * 8;
    const unsigned short* b1 = Bw + (size_t)((w * 2 + 1) * 16 + lr) * D_ + lg * 8;
    const int oA0 = (w * 2 + 0) * 512, oA1 = (w * 2 + 1) * 512;
    const int oB0 = 4096 + oA0,        oB1 = 4096 + oA1;

    auto stage = [&](int ks, int bufi) {
        unsigned short* base = lds + bufi * 8192;
        gload16(a0 + ks * 32, base + oA0);
        gload16(a1 + ks * 32, base + oA1);
        gload16(b0 + ks * 32, base + oB0);
        gload16(b1 + ks * 32, base + oB1);
    };

    stage(0, 0); stage(1, 1);
    for (int ks = 0; ks < 32; ++ks) {
        if (ks < 31) vm_barrier<4>();
        else         vm_barrier<0>();
        if (ks + 2 < 32) stage(ks + 2, (ks + 2) % 3);
        const unsigned short* base = lds + (ks % 3) * 8192;
        bh8 af0 = *(const bh8*)(base + (w * 2 + 0) * 512 + lane * 8);
        bh8 af1 = *(const bh8*)(base + (w * 2 + 1) * 512 + lane * 8);
#pragma unroll
        for (int nt = 0; nt < 8; ++nt) {
            bh8 bf = *(const bh8*)(base + 4096 + nt * 512 + lane * 8);
            acc[0][nt] = mfma16(af0, bf, acc[0][nt]);
            acc[1][nt] = mfma16(af1, bf, acc[1][nt]);
        }
        __builtin_amdgcn_sched_barrier(0);
    }
}

// ---------------- flash attention (causal), swapped-QK^T in-lane softmax ----------------
__global__ __launch_bounds__(256, 4) void k_attn(unsigned short* __restrict__ ws) {
    const int flat = blockIdx.x;          // 0..1023
    const int j    = flat & 31;
    const int qt   = 31 - (flat >> 5);    // heavy tiles first
    const int bh   = (j & 7) * 4 + (j >> 3);
    const int lane = threadIdx.x & 63, w = threadIdx.x >> 6;
    const int lr = lane & 15, lg = lane >> 4;
    const unsigned short* Qp = ws + OFF_Q  + (size_t)bh * E_ * S_;   // Q^T [E][S]
    const unsigned short* Kp = ws + OFF_K  + (size_t)bh * S_ * E_;
    const unsigned short* Vp = ws + OFF_VT + (size_t)bh * E_ * S_;
    __shared__ __align__(16) unsigned short ldsK[2][8 * 512];
    __shared__ __align__(16) unsigned short ldsV[2][8 * 512];
    __shared__ __align__(16) unsigned short ldsP[4 * 1024];   // per-wave 16x64 P (wave-private)

    const int qbase = qt * 64 + w * 16;   // this wave's 16 q rows
    bh8 qf[2];
#pragma unroll
    for (int kg = 0; kg < 2; ++kg) {
        bh8 t;
#pragma unroll
        for (int i = 0; i < 8; ++i)
            t[i] = (short)Qp[(size_t)(kg * 32 + lg * 8 + i) * S_ + qbase + lr];
        qf[kg] = t;
    }

    f32x4 o[4];
    float m = -3.0e38f, l = 0.f;    // per-lane online state for q = lr (replicated over lg)
#pragma unroll
    for (int i = 0; i < 4; ++i) o[i] = (f32x4){0.f, 0.f, 0.f, 0.f};

    auto stage = [&](int kt, int bufi) {
        const int sk0 = kt * 64;
#pragma unroll
        for (int u = 0; u < 2; ++u) {
            const int blk = w * 2 + u;
            const int ct = blk >> 1, kg = blk & 1;
            gload16(Kp + (size_t)(sk0 + ct * 16 + lr) * E_ + kg * 32 + lg * 8,
                    &ldsK[bufi][blk * 512]);
            gload16(Vp + (size_t)(ct * 16 + lr) * S_ + sk0 + kg * 32 + lg * 8,
                    &ldsV[bufi][blk * 512]);
        }
    };

    unsigned short* Pw = ldsP + w * 1024;

    stage(0, 0);
    if (qt >= 1) stage(1, 1);

    for (int kt = 0; kt <= qt; ++kt) {
        if (kt < qt) vm_barrier<4>();
        else         vm_barrier<0>();
        const int cur = kt & 1;
        const unsigned short* Kc = ldsK[cur];
        const unsigned short* Vc = ldsV[cur];

        // S^T = K Q^T (swapped): sc[ct][r] = score[s_k = ct*16+lg*4+r][q = lr]
        f32x4 sc[4];
#pragma unroll
        for (int ct = 0; ct < 4; ++ct) sc[ct] = (f32x4){0.f, 0.f, 0.f, 0.f};
#pragma unroll
        for (int ct = 0; ct < 4; ++ct)
#pragma unroll
            for (int kg = 0; kg < 2; ++kg) {
                bh8 kf = *(const bh8*)(Kc + (ct * 2 + kg) * 512 + lane * 8);
                sc[ct] = mfma16(kf, qf[kg], sc[ct]);
            }
        // causal mask: diagonal tile only; local: s_k = ct*16+lg*4+r, q = w*16+lr
        if (kt == qt) {
#pragma unroll
            for (int ct = 0; ct < 4; ++ct) {
                const int skl = ct * 16 + lg * 4;
#pragma unroll
                for (int r = 0; r < 4; ++r)
                    if (skl + r > w * 16 + lr) sc[ct][r] = -3.0e38f;
            }
        }
        // column (q) max: 15 in-lane fmax + 2 shfl
        float mx = fmaxf(fmaxf(sc[0][0], sc[0][1]), fmaxf(sc[0][2], sc[0][3]));
#pragma unroll
        for (int ct = 1; ct < 4; ++ct)
            mx = fmaxf(mx, fmaxf(fmaxf(sc[ct][0], sc[ct][1]),
                                 fmaxf(sc[ct][2], sc[ct][3])));
        mx = fmaxf(mx, __shfl_xor(mx, 16, 64));
        mx = fmaxf(mx, __shfl_xor(mx, 32, 64));
        // defer-max (T13): rescale only when max grew by > 8 (log2 domain)
        const bool need = mx > m + 8.0f;
        if (__any(need)) {
            const float mn = need ? mx : m;
            const float sf = __builtin_amdgcn_exp2f(m - mn);   // 1.0 when !need
            m = mn;
            l *= sf;
#pragma unroll
            for (int r = 0; r < 4; ++r) {
                const float sfq = __shfl(sf, (lane & 48) + lg * 4 + r, 64);
#pragma unroll
                for (int et = 0; et < 4; ++et) o[et][r] *= sfq;
            }
        }
        // P = exp2(S - m), partial sum in-lane
        float rs = 0.f;
#pragma unroll
        for (int ct = 0; ct < 4; ++ct)
#pragma unroll
            for (int r = 0; r < 4; ++r) {
                float p = __builtin_amdgcn_exp2f(sc[ct][r] - m);
                sc[ct][r] = p;
                rs += p;
            }
        rs += __shfl_xor(rs, 16, 64);
        rs += __shfl_xor(rs, 32, 64);
        l += rs;
        // pack P (cvt_pk) and write A-frag order: 4 x ds_write_b64
#pragma unroll
        for (int ct = 0; ct < 4; ++ct) {
            u32x2 pk = { cvt_pk_bf16(sc[ct][0], sc[ct][1]),
                         cvt_pk_bf16(sc[ct][2], sc[ct][3]) };
            const int addr = (ct >> 1) * 512 +
                             ((((ct & 1) * 2) + (lg >> 1)) * 16 + lr) * 8 + (lg & 1) * 4;
            *(u32x2*)(Pw + addr) = pk;
        }
        // O += P V  (wave-private P; lgkm-ordered, no barrier)
#pragma unroll
        for (int skg = 0; skg < 2; ++skg) {
            bh8 pf = *(const bh8*)(Pw + skg * 512 + lane * 8);
#pragma unroll
            for (int et = 0; et < 4; ++et) {
                bh8 vf = *(const bh8*)(Vc + (et * 2 + skg) * 512 + lane * 8);
                o[et] = mfma16(pf, vf, o[et]);
            }
        }
        post_barrier();
        if (kt + 2 <= qt) stage(kt + 2, cur);
    }
    // epilogue: O/l -> concat layout [B,S,H*64]; l lives at lane with lr = q
    const int b = bh >> 4, hh = bh & 15;
#pragma unroll
    for (int r = 0; r < 4; ++r) {
        const float lq = __shfl(l, (lane & 48) + lg * 4 + r, 64);
        const float inv = 1.0f / lq;
        const int s = qbase + lg * 4 + r;
#pragma unroll
        for (int et = 0; et < 4; ++et)
            ws[OFF_O + ((size_t)(b * S_ + s)) * D_ + hh * E_ + et * 16 + lr] =
                f2bf(o[et][r] * inv);
    }
}

// ---------------- output projection: C[4096,1024] = O * WoT^T ----------------
__global__ __launch_bounds__(256, 3) void k_oproj(const unsigned short* __restrict__ ws,
                                                  const float* __restrict__ bo,
                                                  float* __restrict__ out) {
    const int flat  = blockIdx.x;          // 0..255
    const int idx   = flat >> 3;           // 0..31
    const int stile = (flat & 7) * 4 + (idx & 3);   // 0..31
    const int ntile = idx >> 2;            // 0..7 (128 cols each)
    const unsigned short* A  = ws + OFF_O   + (size_t)stile * 128 * D_;
    const unsigned short* Bw = ws + OFF_WOT + (size_t)ntile * 128 * D_;
    __shared__ __align__(16) unsigned short lds[3 * 8192];
    f32x4 acc[2][8];
#pragma unroll
    for (int i = 0; i < 2; ++i)
#pragma unroll
        for (int j = 0; j < 8; ++j) acc[i][j] = (f32x4){0.f, 0.f, 0.f, 0.f};

    gemm_tile_128x128(A, Bw, lds, acc);

    const int lane = threadIdx.x & 63, w = threadIdx.x >> 6;
    const int lr = lane & 15, lg = lane >> 4;
    const int r0 = stile * 128 + w * 32;
#pragma unroll
    for (int mt = 0; mt < 2; ++mt)
#pragma unroll
        for (int nt = 0; nt < 8; ++nt) {
            const int e = ntile * 128 + nt * 16 + lr;
            const float bia = bo[e];
#pragma unroll
            for (int r = 0; r < 4; ++r)
                out[(size_t)(r0 + mt * 16 + lg * 4 + r) * D_ + e] = acc[mt][nt][r] + bia;
        }
}

extern "C" void kernel_launch(void* const* d_in, const int* in_sizes, int n_in,
                              void* d_out, int out_size, void* d_ws, size_t ws_size,
                              hipStream_t stream) {
    const float* x  = (const float*)d_in[0];
    const float* Wq = (const float*)d_in[1];
    const float* bq = (const float*)d_in[2];
    const float* Wk = (const float*)d_in[3];
    const float* bk = (const float*)d_in[4];
    const float* Wv = (const float*)d_in[5];
    const float* bv = (const float*)d_in[6];
    const float* Wo = (const float*)d_in[7];
    const float* bo = (const float*)d_in[8];
    float* out = (float*)d_out;
    unsigned short* ws = (unsigned short*)d_ws;

    k_convert_x<<<dim3((B_ * S_ * D_) / 4 / 256), 256, 0, stream>>>(x, ws);
    k_transpose_w<<<dim3(256, 4), 256, 0, stream>>>(Wq, Wk, Wv, Wo, ws);
    k_qkv<<<dim3(192), 512, 0, stream>>>(ws, bq, bk, bv);
    k_attn<<<dim3(1024), 256, 0, stream>>>(ws);
    k_oproj<<<dim3(256), 256, 0, stream>>>(ws, bo, out);
}

// Round 14
// 117.948 us; speedup vs baseline: 1.1083x; 1.0080x over previous
//
#include <hip/hip_runtime.h>
#include <stdint.h>

typedef __attribute__((ext_vector_type(8))) short bh8;       // 8 x bf16 (4 VGPR)
typedef __attribute__((ext_vector_type(4))) float f32x4;
typedef __attribute__((ext_vector_type(4))) unsigned short u16x4;
typedef __attribute__((ext_vector_type(8))) unsigned short u16x8;
typedef __attribute__((ext_vector_type(2))) unsigned int u32x2;

#define DEVI static __device__ __forceinline__

constexpr int B_ = 2, S_ = 2048, D_ = 1024, H_ = 16, E_ = 64;

// workspace layout (elements of ushort/bf16)
constexpr size_t OFF_XB  = 0;                              // x as bf16 [B*S, D]
constexpr size_t OFF_WQT = OFF_XB  + (size_t)B_*S_*D_;     // WqT [H, E, D]  } contiguous
constexpr size_t OFF_WKT = OFF_WQT + (size_t)H_*E_*D_;     // WkT [H, E, D]  } = one
constexpr size_t OFF_WVT = OFF_WKT + (size_t)H_*E_*D_;     // WvT [H, E, D]  } [3072,1024]
constexpr size_t OFF_WOT = OFF_WVT + (size_t)H_*E_*D_;     // WoT [D, D]
constexpr size_t OFF_Q   = OFF_WOT + (size_t)D_*D_;        // Q^T [B*H, E, S] (pre-scaled by 0.125*log2e)
constexpr size_t OFF_K   = OFF_Q   + (size_t)B_*H_*S_*E_;  // [B*H, S, E]
constexpr size_t OFF_VT  = OFF_K   + (size_t)B_*H_*S_*E_;  // [B*H, E, S]
constexpr size_t OFF_O   = OFF_VT  + (size_t)B_*H_*S_*E_;  // attn out concat [B*S, D]

DEVI unsigned short f2bf(float f) {
    union { float f; unsigned u; } v; v.f = f;
    unsigned u = v.u;
    return (unsigned short)((u + 0x7fffu + ((u >> 16) & 1u)) >> 16);
}

DEVI unsigned cvt_pk_bf16(float lo, float hi) {   // packs {lo,hi} -> 2 bf16 in one u32
    unsigned r;
    asm("v_cvt_pk_bf16_f32 %0, %1, %2" : "=v"(r) : "v"(lo), "v"(hi));
    return r;
}

DEVI void gload16(const void* g, void* l) {
    __builtin_amdgcn_global_load_lds(
        (const __attribute__((address_space(1))) unsigned int*)g,
        (__attribute__((address_space(3))) unsigned int*)l, 16, 0, 0);
}

DEVI f32x4 mfma16(bh8 a, bh8 b, f32x4 c) {
    return __builtin_amdgcn_mfma_f32_16x16x32_bf16(a, b, c, 0, 0, 0);
}

// counted-vmcnt barrier: prefetched loads stay in flight across the barrier.
template<int N> DEVI void vm_barrier() {
    asm volatile("s_waitcnt vmcnt(%0)" :: "i"(N) : "memory");
    __builtin_amdgcn_s_barrier();
    __builtin_amdgcn_sched_barrier(0);
}
DEVI void post_barrier() {
    __builtin_amdgcn_sched_barrier(0);
    __builtin_amdgcn_s_barrier();
    __builtin_amdgcn_sched_barrier(0);
}

// ---------------- prep: x -> bf16 ----------------
__global__ __launch_bounds__(256) void k_convert_x(const float* __restrict__ x,
                                                   unsigned short* __restrict__ ws) {
    const int i = blockIdx.x * 256 + threadIdx.x;   // one float4 each; n4 = 1048576
    const float4 v = ((const float4*)x)[i];
    u16x4 o = { f2bf(v.x), f2bf(v.y), f2bf(v.z), f2bf(v.w) };
    *(u16x4*)(ws + OFF_XB + (size_t)i * 4) = o;
}

// ---------------- prep: weights -> bf16, transposed ----------------
__global__ __launch_bounds__(256) void k_transpose_w(const float* __restrict__ Wq,
                                                     const float* __restrict__ Wk,
                                                     const float* __restrict__ Wv,
                                                     const float* __restrict__ Wo,
                                                     unsigned short* __restrict__ ws) {
    const int xi = blockIdx.x;   // 0..255
    const int z  = blockIdx.y;   // 0..3
    const int t  = threadIdx.x;
    __shared__ __align__(16) unsigned short tile[64][72];

    const float* src; unsigned short* dst;
    int inCols, inBase, outBase;
    if (z < 3) {
        src = (z == 0) ? Wq : (z == 1) ? Wk : Wv;
        dst = ws + ((z == 0) ? OFF_WQT : (z == 1) ? OFF_WKT : OFF_WVT);
        inCols = 64;
        inBase = xi * 64 * 64;
        const int h = xi >> 4, dt = xi & 15;
        outBase = h * 65536 + dt * 64;
    } else {
        src = Wo; dst = ws + OFF_WOT;
        inCols = 1024;
        const int et = xi >> 4, dt = xi & 15;
        inBase  = (dt * 64) * 1024 + et * 64;
        outBase = (et * 64) * 1024 + dt * 64;
    }
#pragma unroll
    for (int v = 0; v < 4; ++v) {
        const int flat = v * 256 + t;
        const int i = flat >> 4, j4 = (flat & 15) * 4;
        const float4 val = *(const float4*)(src + inBase + i * inCols + j4);
        tile[i][j4 + 0] = f2bf(val.x);
        tile[i][j4 + 1] = f2bf(val.y);
        tile[i][j4 + 2] = f2bf(val.z);
        tile[i][j4 + 3] = f2bf(val.w);
    }
    __syncthreads();
    const int j = t >> 2, iseg = (t & 3) * 16;
    u16x8 p0, p1;
#pragma unroll
    for (int u = 0; u < 8; ++u) p0[u] = tile[iseg + u][j];
#pragma unroll
    for (int u = 0; u < 8; ++u) p1[u] = tile[iseg + 8 + u][j];
    *(u16x8*)(dst + outBase + (size_t)j * 1024 + iseg)     = p0;
    *(u16x8*)(dst + outBase + (size_t)j * 1024 + iseg + 8) = p1;
}

// ================= qkv 256x256 8-phase machinery =================
DEVI void qkv_stA(const unsigned short* Ap, unsigned short* lds, int kt, int mh, int ks,
                  int lane, int w, int lr, int lg) {
    const int b = kt & 1;
    const int mfrag = (w >> 2) * 8 + mh * 4 + (w & 3);
    gload16(Ap + (size_t)(mfrag * 16 + lr) * D_ + kt * 64 + ks * 32 + lg * 8,
            lds + b * 16384 + (mfrag * 2 + ks) * 512 + lane * 8);
}
DEVI void qkv_stB(const unsigned short* Bp, unsigned short* lds, int kt, int ks,
                  int lane, int w, int lr, int lg) {
    const int b = kt & 1;
#pragma unroll
    for (int u = 0; u < 2; ++u) {
        const int nfrag = w * 2 + u;
        gload16(Bp + (size_t)(nfrag * 16 + lr) * D_ + kt * 64 + ks * 32 + lg * 8,
                lds + 32768 + b * 16384 + (nfrag * 2 + ks) * 512 + lane * 8);
    }
}
DEVI bh8 qkv_ldA(const unsigned short* lds, int b, int mfrag, int ks, int lane) {
    return *(const bh8*)(lds + b * 16384 + (mfrag * 2 + ks) * 512 + lane * 8);
}
DEVI bh8 qkv_ldB(const unsigned short* lds, int b, int nfrag, int ks, int lane) {
    return *(const bh8*)(lds + 32768 + b * 16384 + (nfrag * 2 + ks) * 512 + lane * 8);
}

template<int V0, int V1, int V2, int V3, bool S0, bool S123>
DEVI void qkv_ktile(int kt, const unsigned short* Ap, const unsigned short* Bp,
                    unsigned short* lds, int lane, int w, int lr, int lg,
                    int wm, int wn, f32x4 (&acc)[8][4]) {
    const int b = kt & 1;
    bh8 af[4], bf[4];
    // ---- phase 0: quad(mh=0, ks=0); stage A(1,1) of kt+1 ----
    vm_barrier<V0>();
#pragma unroll
    for (int n = 0; n < 4; ++n) bf[n] = qkv_ldB(lds, b, wn * 4 + n, 0, lane);
#pragma unroll
    for (int q = 0; q < 4; ++q) af[q] = qkv_ldA(lds, b, wm * 8 + q, 0, lane);
    if (S0) qkv_stA(Ap, lds, kt + 1, 1, 1, lane, w, lr, lg);
    __builtin_amdgcn_s_setprio(1);
#pragma unroll
    for (int q = 0; q < 4; ++q)
#pragma unroll
        for (int n = 0; n < 4; ++n) acc[q][n] = mfma16(af[q], bf[n], acc[q][n]);
    __builtin_amdgcn_s_setprio(0);
    __builtin_amdgcn_sched_barrier(0);
    // ---- phase 1: quad(1,0); stage A(0,0)+B(ks0) of kt+2 ----
    vm_barrier<V1>();
#pragma unroll
    for (int q = 0; q < 4; ++q) af[q] = qkv_ldA(lds, b, wm * 8 + 4 + q, 0, lane);
    if (S123) {
        qkv_stA(Ap, lds, kt + 2, 0, 0, lane, w, lr, lg);
        qkv_stB(Bp, lds, kt + 2, 0, lane, w, lr, lg);
    }
    __builtin_amdgcn_s_setprio(1);
#pragma unroll
    for (int q = 0; q < 4; ++q)
#pragma unroll
        for (int n = 0; n < 4; ++n) acc[4 + q][n] = mfma16(af[q], bf[n], acc[4 + q][n]);
    __builtin_amdgcn_s_setprio(0);
    __builtin_amdgcn_sched_barrier(0);
    // ---- phase 2: quad(0,1); stage A(1,0) of kt+2 ----
    vm_barrier<V2>();
#pragma unroll
    for (int n = 0; n < 4; ++n) bf[n] = qkv_ldB(lds, b, wn * 4 + n, 1, lane);
#pragma unroll
    for (int q = 0; q < 4; ++q) af[q] = qkv_ldA(lds, b, wm * 8 + q, 1, lane);
    if (S123) qkv_stA(Ap, lds, kt + 2, 1, 0, lane, w, lr, lg);
    __builtin_amdgcn_s_setprio(1);
#pragma unroll
    for (int q = 0; q < 4; ++q)
#pragma unroll
        for (int n = 0; n < 4; ++n) acc[q][n] = mfma16(af[q], bf[n], acc[q][n]);
    __builtin_amdgcn_s_setprio(0);
    __builtin_amdgcn_sched_barrier(0);
    // ---- phase 3: quad(1,1); stage A(0,1)+B(ks1) of kt+2 ----
    vm_barrier<V3>();
#pragma unroll
    for (int q = 0; q < 4; ++q) af[q] = qkv_ldA(lds, b, wm * 8 + 4 + q, 1, lane);
    if (S123) {
        qkv_stA(Ap, lds, kt + 2, 0, 1, lane, w, lr, lg);
        qkv_stB(Bp, lds, kt + 2, 1, lane, w, lr, lg);
    }
    __builtin_amdgcn_s_setprio(1);
#pragma unroll
    for (int q = 0; q < 4; ++q)
#pragma unroll
        for (int n = 0; n < 4; ++n) acc[4 + q][n] = mfma16(af[q], bf[n], acc[4 + q][n]);
    __builtin_amdgcn_s_setprio(0);
    __builtin_amdgcn_sched_barrier(0);
}

// ---------------- fused QKV projection: 256x256 tiles, 8 waves, 8-phase ----------------
__global__ __launch_bounds__(512, 2) void k_qkv(unsigned short* __restrict__ ws,
                                                const float* __restrict__ bq,
                                                const float* __restrict__ bk,
                                                const float* __restrict__ bv) {
    const int flat  = blockIdx.x;                   // 0..191
    const int idx   = flat >> 3;                    // 0..23
    const int stile = (flat & 7) * 2 + (idx & 1);   // 0..15 (256 rows each)
    const int ntile = idx >> 1;                     // 0..11 (256 cols each of 3072)
    const unsigned short* Ap = ws + OFF_XB  + (size_t)stile * 256 * D_;
    const unsigned short* Bp = ws + OFF_WQT + (size_t)ntile * 256 * D_;

    __shared__ __align__(16) unsigned short lds[65536];   // 128 KB
    const int tid = threadIdx.x, lane = tid & 63, w = tid >> 6;
    const int lr = lane & 15, lg = lane >> 4;
    const int wm = w >> 2, wn = w & 3;               // wave tile: rows wm*128, cols wn*64

    f32x4 acc[8][4];
#pragma unroll
    for (int i = 0; i < 8; ++i)
#pragma unroll
        for (int j = 0; j < 4; ++j) acc[i][j] = (f32x4){0.f, 0.f, 0.f, 0.f};

    // prologue: kt0 full (8) + kt1 minus A(1,1) (7), in steady-state FIFO order
    qkv_stA(Ap, lds, 0, 0, 0, lane, w, lr, lg);
    qkv_stB(Bp, lds, 0, 0, lane, w, lr, lg);
    qkv_stA(Ap, lds, 0, 1, 0, lane, w, lr, lg);
    qkv_stA(Ap, lds, 0, 0, 1, lane, w, lr, lg);
    qkv_stB(Bp, lds, 0, 1, lane, w, lr, lg);
    qkv_stA(Ap, lds, 0, 1, 1, lane, w, lr, lg);
    qkv_stA(Ap, lds, 1, 0, 0, lane, w, lr, lg);
    qkv_stB(Bp, lds, 1, 0, lane, w, lr, lg);
    qkv_stA(Ap, lds, 1, 1, 0, lane, w, lr, lg);
    qkv_stA(Ap, lds, 1, 0, 1, lane, w, lr, lg);
    qkv_stB(Bp, lds, 1, 1, lane, w, lr, lg);

    for (int kt = 0; kt < 14; ++kt)
        qkv_ktile<12, 12, 12, 12, true, true>(kt, Ap, Bp, lds, lane, w, lr, lg, wm, wn, acc);
    qkv_ktile<12, 12, 9, 8, true, false>(14, Ap, Bp, lds, lane, w, lr, lg, wm, wn, acc);
    qkv_ktile<5, 4, 1, 0, false, false>(15, Ap, Bp, lds, lane, w, lr, lg, wm, wn, acc);

    // epilogue: wave writes one head's 64-col slab. c = ntile*4+wn in 0..47
    const int c = ntile * 4 + wn;
    const int mat = c >> 4, h = c & 15;
    const float* bias = ((mat == 0) ? bq : (mat == 1) ? bk : bv) + h * 64;
    const int bb = stile >> 3;                       // batch (256 | 2048, no straddle)
    const int bh = bb * H_ + h;
#pragma unroll
    for (int mf = 0; mf < 8; ++mf) {
        const int sl = ((stile * 256 + wm * 128 + mf * 16) & (S_ - 1)) + lg * 4;
#pragma unroll
        for (int nf = 0; nf < 4; ++nf) {
            const int e = nf * 16 + lr;
            const float bia = bias[e];
            if (mat == 0) {        // Q^T [BH][E][S], pre-scaled by 0.125*log2e
                u16x4 pk;
#pragma unroll
                for (int r = 0; r < 4; ++r)
                    pk[r] = f2bf((acc[mf][nf][r] + bia) * 0.1803368801f);
                *(u16x4*)(ws + OFF_Q + ((size_t)(bh * E_ + e)) * S_ + sl) = pk;
            } else if (mat == 2) { // V^T [BH][E][S]
                u16x4 pk;
#pragma unroll
                for (int r = 0; r < 4; ++r) pk[r] = f2bf(acc[mf][nf][r] + bia);
                *(u16x4*)(ws + OFF_VT + ((size_t)(bh * E_ + e)) * S_ + sl) = pk;
            } else {               // K [BH][S][E]
#pragma unroll
                for (int r = 0; r < 4; ++r)
                    ws[OFF_K + ((size_t)bh * S_ + sl + r) * E_ + e] =
                        f2bf(acc[mf][nf][r] + bia);
            }
        }
    }
}

// ---------------- GEMM mainloop: C(128x128) (oproj) ----------------
DEVI void gemm_tile_128x128(const unsigned short* __restrict__ A,
                            const unsigned short* __restrict__ Bw,
                            unsigned short* lds,
                            f32x4 acc[2][8]) {
    const int lane = threadIdx.x & 63;
    const int w    = threadIdx.x >> 6;
    const int lr = lane & 15, lg = lane >> 4;
    const unsigned short* a0 = A  + (size_t)((w * 2 + 0) * 16 + lr) * D_ + lg * 8;
    const unsigned short* a1 = A  + (size_t)((w * 2 + 1) * 16 + lr) * D_ + lg * 8;
    const unsigned short* b0 = Bw + (size_t)((w * 2 + 0) * 16 + lr) * D_ + lg * 8;
    const unsigned short* b1 = Bw + (size_t)((w * 2 + 1) * 16 + lr) * D_ + lg * 8;
    const int oA0 = (w * 2 + 0) * 512, oA1 = (w * 2 + 1) * 512;
    const int oB0 = 4096 + oA0,        oB1 = 4096 + oA1;

    auto stage = [&](int ks, int bufi) {
        unsigned short* base = lds + bufi * 8192;
        gload16(a0 + ks * 32, base + oA0);
        gload16(a1 + ks * 32, base + oA1);
        gload16(b0 + ks * 32, base + oB0);
        gload16(b1 + ks * 32, base + oB1);
    };

    stage(0, 0); stage(1, 1);
    for (int ks = 0; ks < 32; ++ks) {
        if (ks < 31) vm_barrier<4>();
        else         vm_barrier<0>();
        if (ks + 2 < 32) stage(ks + 2, (ks + 2) % 3);
        const unsigned short* base = lds + (ks % 3) * 8192;
        bh8 af0 = *(const bh8*)(base + (w * 2 + 0) * 512 + lane * 8);
        bh8 af1 = *(const bh8*)(base + (w * 2 + 1) * 512 + lane * 8);
#pragma unroll
        for (int nt = 0; nt < 8; ++nt) {
            bh8 bf = *(const bh8*)(base + 4096 + nt * 512 + lane * 8);
            acc[0][nt] = mfma16(af0, bf, acc[0][nt]);
            acc[1][nt] = mfma16(af1, bf, acc[1][nt]);
        }
        __builtin_amdgcn_sched_barrier(0);
    }
}

// ---------------- flash attention (causal), swapped-QK^T, KVBLK=128 ----------------
// 2 barriers per 128-wide k-tile (32 MFMA per sync interval, was 16 per 64-wide).
// LDS 80 KB -> 2 blocks/CU; staging bytes unchanged (FETCH stays ~12 MB).
__global__ __launch_bounds__(256, 2) void k_attn(unsigned short* __restrict__ ws) {
    const int flat = blockIdx.x;          // 0..1023
    const int j    = flat & 31;
    const int qt   = 31 - (flat >> 5);    // heavy tiles first
    const int bh   = (j & 7) * 4 + (j >> 3);
    const int lane = threadIdx.x & 63, w = threadIdx.x >> 6;
    const int lr = lane & 15, lg = lane >> 4;
    const unsigned short* Qp = ws + OFF_Q  + (size_t)bh * E_ * S_;   // Q^T [E][S]
    const unsigned short* Kp = ws + OFF_K  + (size_t)bh * S_ * E_;
    const unsigned short* Vp = ws + OFF_VT + (size_t)bh * E_ * S_;
    __shared__ __align__(16) unsigned short ldsK[2][16 * 512];   // 128x64 K tile, frag order
    __shared__ __align__(16) unsigned short ldsV[2][16 * 512];   // 64x128 V^T tile
    __shared__ __align__(16) unsigned short ldsP[4 * 2048];      // per-wave 16x128 P

    const int qbase = qt * 64 + w * 16;   // this wave's 16 q rows
    bh8 qf[2];
#pragma unroll
    for (int kg = 0; kg < 2; ++kg) {
        bh8 t;
#pragma unroll
        for (int i = 0; i < 8; ++i)
            t[i] = (short)Qp[(size_t)(kg * 32 + lg * 8 + i) * S_ + qbase + lr];
        qf[kg] = t;
    }

    f32x4 o[4];
    float m = -3.0e38f, l = 0.f;    // per-lane online state for q = lr (replicated over lg)
#pragma unroll
    for (int i = 0; i < 4; ++i) o[i] = (f32x4){0.f, 0.f, 0.f, 0.f};

    // per wave: 4 K-frags + 4 V-frags (blk = w*4+u in 0..15; LDS slot = blk*512 both)
    auto stage = [&](int kt, int bufi) {
        const int sk0 = kt * 128;
#pragma unroll
        for (int u = 0; u < 4; ++u) {
            const int blk = w * 4 + u;
            const int ct = blk >> 1, kg = blk & 1;       // K frag (ct, kg)
            gload16(Kp + (size_t)(sk0 + ct * 16 + lr) * E_ + kg * 32 + lg * 8,
                    &ldsK[bufi][blk * 512]);
            const int et = blk >> 2, skg = blk & 3;      // V frag (et, skg)
            gload16(Vp + (size_t)(et * 16 + lr) * S_ + sk0 + skg * 32 + lg * 8,
                    &ldsV[bufi][blk * 512]);
        }
    };

    unsigned short* Pw = ldsP + w * 2048;
    const int nkt = (qt >> 1) + 1;

    stage(0, 0);
    if (nkt > 1) stage(1, 1);

    for (int kt = 0; kt < nkt; ++kt) {
        if (kt + 1 < nkt) vm_barrier<8>();
        else              vm_barrier<0>();
        const int cur = kt & 1;
        const unsigned short* Kc = ldsK[cur];
        const unsigned short* Vc = ldsV[cur];

        // S^T = K Q^T (swapped): sc[ct][r] = score[s_k = kt*128+ct*16+lg*4+r][q = lr]
        f32x4 sc[8];
#pragma unroll
        for (int ct = 0; ct < 8; ++ct) sc[ct] = (f32x4){0.f, 0.f, 0.f, 0.f};
#pragma unroll
        for (int ct = 0; ct < 8; ++ct)
#pragma unroll
            for (int kg = 0; kg < 2; ++kg) {
                bh8 kf = *(const bh8*)(Kc + (ct * 2 + kg) * 512 + lane * 8);
                sc[ct] = mfma16(kf, qf[kg], sc[ct]);
            }
        // causal mask: last tile only. off = qt*64 - kt*128 (0 for even qt, 64 for odd)
        if (kt == nkt - 1) {
            const int off = qt * 64 - kt * 128 + w * 16 + lr;
#pragma unroll
            for (int ct = 0; ct < 8; ++ct) {
                const int skl = ct * 16 + lg * 4;
#pragma unroll
                for (int r = 0; r < 4; ++r)
                    if (skl + r > off) sc[ct][r] = -3.0e38f;
            }
        }
        // column (q) max: 31 in-lane fmax + 2 shfl
        float mx = fmaxf(fmaxf(sc[0][0], sc[0][1]), fmaxf(sc[0][2], sc[0][3]));
#pragma unroll
        for (int ct = 1; ct < 8; ++ct)
            mx = fmaxf(mx, fmaxf(fmaxf(sc[ct][0], sc[ct][1]),
                                 fmaxf(sc[ct][2], sc[ct][3])));
        mx = fmaxf(mx, __shfl_xor(mx, 16, 64));
        mx = fmaxf(mx, __shfl_xor(mx, 32, 64));
        // defer-max (T13): rescale only when max grew by > 8 (log2 domain)
        const bool need = mx > m + 8.0f;
        if (__any(need)) {
            const float mn = need ? mx : m;
            const float sf = __builtin_amdgcn_exp2f(m - mn);   // 1.0 when !need
            m = mn;
            l *= sf;
#pragma unroll
            for (int r = 0; r < 4; ++r) {
                const float sfq = __shfl(sf, (lane & 48) + lg * 4 + r, 64);
#pragma unroll
                for (int et = 0; et < 4; ++et) o[et][r] *= sfq;
            }
        }
        // P = exp2(S - m), partial sum in-lane
        float rs = 0.f;
#pragma unroll
        for (int ct = 0; ct < 8; ++ct)
#pragma unroll
            for (int r = 0; r < 4; ++r) {
                float p = __builtin_amdgcn_exp2f(sc[ct][r] - m);
                sc[ct][r] = p;
                rs += p;
            }
        rs += __shfl_xor(rs, 16, 64);
        rs += __shfl_xor(rs, 32, 64);
        l += rs;
        // pack P (cvt_pk) and write A-frag order: 8 x ds_write_b64
#pragma unroll
        for (int ct = 0; ct < 8; ++ct) {
            u32x2 pk = { cvt_pk_bf16(sc[ct][0], sc[ct][1]),
                         cvt_pk_bf16(sc[ct][2], sc[ct][3]) };
            const int addr = (ct >> 1) * 512 +
                             ((((ct & 1) * 2) + (lg >> 1)) * 16 + lr) * 8 + (lg & 1) * 4;
            *(u32x2*)(Pw + addr) = pk;
        }
        // O += P V  (wave-private P; lgkm-ordered, no barrier)
#pragma unroll
        for (int skg = 0; skg < 4; ++skg) {
            bh8 pf = *(const bh8*)(Pw + skg * 512 + lane * 8);
#pragma unroll
            for (int et = 0; et < 4; ++et) {
                bh8 vf = *(const bh8*)(Vc + (et * 4 + skg) * 512 + lane * 8);
                o[et] = mfma16(pf, vf, o[et]);
            }
        }
        post_barrier();
        if (kt + 2 < nkt) stage(kt + 2, cur);
    }
    // epilogue: O/l -> concat layout [B,S,H*64]; l lives at lane with lr = q
    const int b = bh >> 4, hh = bh & 15;
#pragma unroll
    for (int r = 0; r < 4; ++r) {
        const float lq = __shfl(l, (lane & 48) + lg * 4 + r, 64);
        const float inv = 1.0f / lq;
        const int s = qbase + lg * 4 + r;
#pragma unroll
        for (int et = 0; et < 4; ++et)
            ws[OFF_O + ((size_t)(b * S_ + s)) * D_ + hh * E_ + et * 16 + lr] =
                f2bf(o[et][r] * inv);
    }
}

// ---------------- output projection: C[4096,1024] = O * WoT^T ----------------
__global__ __launch_bounds__(256, 3) void k_oproj(const unsigned short* __restrict__ ws,
                                                  const float* __restrict__ bo,
                                                  float* __restrict__ out) {
    const int flat  = blockIdx.x;          // 0..255
    const int idx   = flat >> 3;           // 0..31
    const int stile = (flat & 7) * 4 + (idx & 3);   // 0..31
    const int ntile = idx >> 2;            // 0..7 (128 cols each)
    const unsigned short* A  = ws + OFF_O   + (size_t)stile * 128 * D_;
    const unsigned short* Bw = ws + OFF_WOT + (size_t)ntile * 128 * D_;
    __shared__ __align__(16) unsigned short lds[3 * 8192];
    f32x4 acc[2][8];
#pragma unroll
    for (int i = 0; i < 2; ++i)
#pragma unroll
        for (int j = 0; j < 8; ++j) acc[i][j] = (f32x4){0.f, 0.f, 0.f, 0.f};

    gemm_tile_128x128(A, Bw, lds, acc);

    const int lane = threadIdx.x & 63, w = threadIdx.x >> 6;
    const int lr = lane & 15, lg = lane >> 4;
    const int r0 = stile * 128 + w * 32;
#pragma unroll
    for (int mt = 0; mt < 2; ++mt)
#pragma unroll
        for (int nt = 0; nt < 8; ++nt) {
            const int e = ntile * 128 + nt * 16 + lr;
            const float bia = bo[e];
#pragma unroll
            for (int r = 0; r < 4; ++r)
                out[(size_t)(r0 + mt * 16 + lg * 4 + r) * D_ + e] = acc[mt][nt][r] + bia;
        }
}

extern "C" void kernel_launch(void* const* d_in, const int* in_sizes, int n_in,
                              void* d_out, int out_size, void* d_ws, size_t ws_size,
                              hipStream_t stream) {
    const float* x  = (const float*)d_in[0];
    const float* Wq = (const float*)d_in[1];
    const float* bq = (const float*)d_in[2];
    const float* Wk = (const float*)d_in[3];
    const float* bk = (const float*)d_in[4];
    const float* Wv = (const float*)d_in[5];
    const float* bv = (const float*)d_in[6];
    const float* Wo = (const float*)d_in[7];
    const float* bo = (const float*)d_in[8];
    float* out = (float*)d_out;
    unsigned short* ws = (unsigned short*)d_ws;

    k_convert_x<<<dim3((B_ * S_ * D_) / 4 / 256), 256, 0, stream>>>(x, ws);
    k_transpose_w<<<dim3(256, 4), 256, 0, stream>>>(Wq, Wk, Wv, Wo, ws);
    k_qkv<<<dim3(192), 512, 0, stream>>>(ws, bq, bk, bv);
    k_attn<<<dim3(1024), 256, 0, stream>>>(ws);
    k_oproj<<<dim3(256), 256, 0, stream>>>(ws, bo, out);
}